// Round 10
// baseline (378.893 us; speedup 1.0000x reference)
//
#include <hip/hip_runtime.h>

// Exact-order float32 arithmetic: numpy/jax evaluate left-to-right with no
// FMA contraction. hipcc defaults to -ffp-contract=fast, which would change
// rounding -> possible spike-time shift -> large voltage absmax error.
#pragma clang fp contract(off)

// R10: 2-step speculation - ONE ballot/SALU round trip per TWO steps.
// 29 ballot slots (lane = slot):
//   g0 LLBN lanes 0..4   : 0 = step-t fire (I2(t) uniform-known);
//                          1..4 = step-t+1 fire for (a=z2,b=z4) combos
//   g1 EBN  lanes 5..10  : 5,6 = step-t variants (z2=0,1);
//                          7..10 = t+1 combos (a=z2 post, b=z2' I-variant)
//   g2 IFN  lanes 11..16 : 11,12 = t (z3=0,1); 13..16 = t+1 (a=z3,b=z3')
//   g3 TN   lanes 17..22 : 17,18 = t (z3=0,1); 19..22 = t+1 (a=z3,b=z3')
//   g4 MN   lanes 23..28 : 23,24 = t (z5=0,1); 25..28 = t+1 (a=z5,b=z5')
// Every lane of a group computes the full local candidate tree (both
// I(t)-variant posts, then 4 post(t+1) candidates) - parallel work, no
// extra chain depth - and contributes its slot's v1 to the single ballot.
// SALU resolves z2,z3,z4,z5,z6 and z2'..z6', builds masks mA (step-t
// control bit per group; z2 for LLBN) and mB (step-t+1 control bit; z4 for
// LLBN), and each lane adopts the actual post(t+1) via a 3-cndmask tree.
// All candidates use the validated constant-I set with the reference's
// exact op order -> bit-exact (absmax 0.0 through R9).
// Cycle detection: rolling-40 anchor + Brent pow-2 fallback (as R9).

__device__ __forceinline__ float sel_mask(float a, float b, unsigned long long m) {
    float r;
    // D = m.bit[lane] ? S1 : S0   (VOP3 v_cndmask with SGPR-pair condition)
    asm("v_cndmask_b32 %0, %1, %2, %3" : "=v"(r) : "v"(a), "v"(b), "s"(m));
    return r;
}

__device__ __forceinline__ int mbit(unsigned long long m, int k) {
    return (int)((m >> k) & 1ull);
}

__global__ __launch_bounds__(256) void net_sim(const float* __restrict__ mat,
                                               const float* __restrict__ w,
                                               float* __restrict__ out,
                                               int* __restrict__ ws,
                                               int T) {
    __shared__ double red[256];
    const int tid = threadIdx.x;

    // ---- z_plus = sum(input_mat * w0), f32 products accumulated in f64 ----
    const float w0 = w[0];
    double s = 0.0;
    for (int i = tid; i < 127 * 127; i += 256) {
        float p = mat[i] * w0;   // elementwise product rounded to f32 (as ref)
        s += (double)p;
    }
    red[tid] = s;
    __syncthreads();
    #pragma unroll
    for (int off = 128; off > 0; off >>= 1) {
        if (tid < off) red[tid] += red[tid + off];
        __syncthreads();
    }
    if (tid >= 29) return;   // 29 lanes of wave 0 continue; no more barriers

    const float z_plus = (float)red[0];

    const float w2 = w[2], w3 = w[3], w5 = w[5], w6 = w[6], w7 = w[7],
                w8 = w[8], w9 = w[9], w10 = w[10], w11 = w[11];
    const float zp_w1 = z_plus * w[1];
    const float zp_w4 = z_plus * w[4];

    // Validated constant-I set (R2..R9, absmax 0.0). z*w is exactly +0.0f
    // or w; x + (+0.0f) == x for the values involved.
    const float I2_00 = w2 * (zp_w1 - 0.0f) + w3 * 0.0f;   // (z2p, z4p)
    const float I2_10 = w2 * (zp_w1 - 0.0f) + w3 * 1.0f;
    const float I2_01 = w2 * (zp_w1 - w7)   + w3 * 0.0f;
    const float I2_11 = w2 * (zp_w1 - w7)   + w3 * 1.0f;
    const float I3_0  = zp_w4 + 0.0f * w5;
    const float I3_1  = zp_w4 + 1.0f * w5;
    const float I4_0  = 0.0f * w6;
    const float I4_1  = 1.0f * w6;
    const float I5_00 = w9 * (0.0f * w8) + w10 * 0.0f;     // (z3, z5p)
    const float I5_10 = w9 * (1.0f * w8) + w10 * 0.0f;
    const float I5_01 = w9 * (0.0f * w8) + w10 * 1.0f;
    const float I5_11 = w9 * (1.0f * w8) + w10 * 1.0f;
    const float I6_0  = 0.0f * w11;
    const float I6_1  = 1.0f * w11;

    const int lane = tid;  // 0..28
    const int g = lane < 5 ? 0 : lane < 11 ? 1 : lane < 17 ? 2
                : lane < 23 ? 3 : 4;
    const int Bg = g == 0 ? 0 : g == 1 ? 5 : g == 2 ? 11 : g == 3 ? 17 : 23;
    const int r  = lane - Bg;

    // per-lane params; ka = float(TAU*DT*a) computed in f64 like Python
    const float ka = g == 0 ? (float)(0.25 * 0.1) : (float)(0.25 * 0.02);
    const float b  = g == 0 ? -0.075f : (g == 3 ? 0.2f : 0.25f);
    const float c  = g <= 1 ? -55.0f : -65.0f;
    const float d  = g == 1 ? 0.05f : 6.0f;
    float v = g == 0 ? -60.0f : (g == 3 ? -70.0f : -64.0f);
    float u = g == 0 ? 4.5f   : (g == 3 ? -14.0f : -16.0f);

    // step-t I-variant constants (a: z5p=0, b: z5p=1; TN differs).
    const float C0a = g == 1 ? I3_0 : g == 2 ? I4_0 : g == 3 ? I5_00
                    : g == 4 ? I6_0 : I2_00;
    const float C0b = g == 3 ? I5_01 : C0a;
    const float C1a = g == 1 ? I3_1 : g == 2 ? I4_1 : g == 3 ? I5_10
                    : g == 4 ? I6_1 : I2_00;
    const float C1b = g == 3 ? I5_11 : C1a;

    // step-t+1 I constants per (a,b) combo for groups 0,1,2,4 (TN = runtime)
    const float Q00 = g == 0 ? I2_00 : g == 1 ? I3_0 : g == 2 ? I4_0 : I6_0;
    const float Q10 = g == 0 ? I2_10 : Q00;
    const float Q01 = g == 0 ? I2_01 : g == 1 ? I3_1 : g == 2 ? I4_1 : I6_1;
    const float Q11 = g == 0 ? I2_11 : Q01;

    const bool is_g0 = (g == 0);
    const bool is_g3 = (g == 3);

    // ballot-slot selection flags (lane constants)
    const bool sel_t   = is_g0 ? (r == 0) : (r < 2);
    const bool sel_tv1 = (!is_g0) && (r == 1);
    const int  ci      = is_g0 ? (r - 1) : (r - 2);   // t+1 combo idx (may be <0)
    const bool slot_a  = (ci & 1) != 0;
    const bool slot_b  = (ci & 2) != 0;

    float* __restrict__ psp = out + g * T;           // spikes row
    float* __restrict__ pvv = out + 5 * T + g * T;   // volts row

    int z2c = 0, z4c = 0, z5c = 0;   // carry bits entering step t (uniform)

    // ---- cycle-detection: rolling-40 anchor + Brent pow-2 fallback ----
    float rav = 0.0f, rau = 0.0f; int raz2 = 0, raz4 = 0, raz5 = 0, ra_t = -1;
    float cav = 0.0f, cau = 0.0f; int caz2 = 0, caz4 = 0, caz5 = 0, ca_t = -1;
    int next_coarse = 8;
    int t_det = -1, Pf = 0;

    float zb[8], vb[8];

    int t = 0;
    for (; t + 8 <= T; t += 8) {
        // ---- block top: anchor compares / refresh ----
        if (t % 40 == 0) {
            if (ra_t >= 0) {
                unsigned long long mv =
                    __ballot(__float_as_uint(v) == __float_as_uint(rav));
                unsigned long long mu =
                    __ballot(__float_as_uint(u) == __float_as_uint(rau));
                if (((mv & mu) & 0x1FFFFFFFull) == 0x1FFFFFFFull &&
                    z2c == raz2 && z4c == raz4 && z5c == raz5) {
                    t_det = t; Pf = t - ra_t;   // Pf == 40
                    break;
                }
            }
            if (t) { rav = v; rau = u; raz2 = z2c; raz4 = z4c; raz5 = z5c; ra_t = t; }
        } else if (ca_t >= 0) {
            unsigned long long mv =
                __ballot(__float_as_uint(v) == __float_as_uint(cav));
            unsigned long long mu =
                __ballot(__float_as_uint(u) == __float_as_uint(cau));
            if (((mv & mu) & 0x1FFFFFFFull) == 0x1FFFFFFFull &&
                z2c == caz2 && z4c == caz4 && z5c == caz5) {
                t_det = t; Pf = t - ca_t;
                break;
            }
        }
        if (t == next_coarse) {
            cav = v; cau = u; caz2 = z2c; caz4 = z4c; caz5 = z5c; ca_t = t;
            next_coarse <<= 1;
        }

        #pragma unroll
        for (int j = 0; j < 4; ++j) {     // 4 x 2 steps = 8 steps
            // ===== step t: both I-variant updates =====
            float fI2 = z4c ? (z2c ? I2_11 : I2_01) : (z2c ? I2_10 : I2_00);
            float J0 = z5c ? C0b : C0a;
            float J1 = z5c ? C1b : C1a;
            J0 = is_g0 ? fI2 : J0;
            J1 = is_g0 ? fI2 : J1;

            float t1 = 0.04f * v;
            float t2 = t1 * v;
            float t3 = 5.0f * v;
            float t4 = t2 + t3;
            float t5 = t4 + 140.0f;
            float t6 = t5 - u;
            float bv = b * v;
            float bvu = bv - u;
            float du = ka * bvu;
            float u1 = u + du;
            float u1d = u1 + d;

            float t7_0 = t6 + J0;
            float dv_0 = 0.25f * t7_0;   // TAU*DT = 0.25 exactly
            float v1t0 = v + dv_0;
            float t7_1 = t6 + J1;
            float dv_1 = 0.25f * t7_1;
            float v1t1 = v + dv_1;
            bool f0 = (v1t0 >= 30.0f);
            bool f1 = (v1t1 >= 30.0f);
            float vt0 = f0 ? c : v1t0;
            float ut0 = f0 ? u1d : u1;   // z*d is exactly d or +0.0f
            float vt1 = f1 ? c : v1t1;
            float ut1 = f1 ? u1d : u1;
            float zt0 = f0 ? 1.0f : 0.0f;
            float zt1 = f1 ? 1.0f : 0.0f;

            // ===== step t+1 candidate I's =====
            float Ip00 = Q00, Ip10 = Q10, Ip01 = Q01, Ip11 = Q11;
            {   // TN: I5' = f(b=z3', z5(t)=fire of post-variant a)
                float tn00 = f0 ? I5_01 : I5_00;
                float tn10 = f1 ? I5_01 : I5_00;
                float tn01 = f0 ? I5_11 : I5_10;
                float tn11 = f1 ? I5_11 : I5_10;
                Ip00 = is_g3 ? tn00 : Ip00;
                Ip10 = is_g3 ? tn10 : Ip10;
                Ip01 = is_g3 ? tn01 : Ip01;
                Ip11 = is_g3 ? tn11 : Ip11;
            }

            // ===== step t+1: heads from both posts, 4 tails =====
            float a1 = 0.04f * vt0;
            float a2 = a1 * vt0;
            float a3 = 5.0f * vt0;
            float a4 = a2 + a3;
            float a5 = a4 + 140.0f;
            float a6 = a5 - ut0;
            float abv = b * vt0;
            float abvu = abv - ut0;
            float adu = ka * abvu;
            float u1n0 = ut0 + adu;
            float u1dn0 = u1n0 + d;

            float e1 = 0.04f * vt1;
            float e2 = e1 * vt1;
            float e3 = 5.0f * vt1;
            float e4 = e2 + e3;
            float e5 = e4 + 140.0f;
            float e6 = e5 - ut1;
            float ebv = b * vt1;
            float ebvu = ebv - ut1;
            float edu = ka * ebvu;
            float u1n1 = ut1 + edu;
            float u1dn1 = u1n1 + d;

            float p00 = a6 + Ip00; float q00 = 0.25f * p00; float v1n00 = vt0 + q00;
            float p10 = e6 + Ip10; float q10 = 0.25f * p10; float v1n10 = vt1 + q10;
            float p01 = a6 + Ip01; float q01 = 0.25f * p01; float v1n01 = vt0 + q01;
            float p11 = e6 + Ip11; float q11 = 0.25f * p11; float v1n11 = vt1 + q11;
            bool fn00 = (v1n00 >= 30.0f);
            bool fn10 = (v1n10 >= 30.0f);
            bool fn01 = (v1n01 >= 30.0f);
            bool fn11 = (v1n11 >= 30.0f);
            float vn00 = fn00 ? c : v1n00;  float un00 = fn00 ? u1dn0 : u1n0;
            float vn10 = fn10 ? c : v1n10;  float un10 = fn10 ? u1dn1 : u1n1;
            float vn01 = fn01 ? c : v1n01;  float un01 = fn01 ? u1dn0 : u1n0;
            float vn11 = fn11 ? c : v1n11;  float un11 = fn11 ? u1dn1 : u1n1;
            float zn00 = fn00 ? 1.0f : 0.0f;
            float zn10 = fn10 ? 1.0f : 0.0f;
            float zn01 = fn01 ? 1.0f : 0.0f;
            float zn11 = fn11 ? 1.0f : 0.0f;

            // ===== ballot: each lane contributes its slot's v1 =====
            float btv = sel_tv1 ? v1t1 : v1t0;
            float bn0 = slot_b ? v1n01 : v1n00;
            float bn1 = slot_b ? v1n11 : v1n10;
            float bnv = slot_a ? bn1 : bn0;
            float bval = sel_t ? btv : bnv;
            unsigned long long m = __ballot(bval >= 30.0f);

            // ===== SALU: resolve both steps' bits =====
            int z2 = mbit(m, 0);
            int z3 = mbit(m, 5 + z2);
            int z4 = mbit(m, 11 + z3);
            int z5 = mbit(m, 17 + z3);
            int z2n = mbit(m, 1 + z2 + 2 * z4);
            int z3n = mbit(m, 7 + z2 + 2 * z2n);
            int z4n = mbit(m, 13 + z3 + 2 * z3n);
            int z5n = mbit(m, 19 + z3 + 2 * z3n);

            unsigned long long mA =
                (z2 ? 0x7FFull : 0ull) | (z3 ? 0x7FF800ull : 0ull)
              | (z5 ? 0x1F800000ull : 0ull);
            unsigned long long mB =
                (z4 ? 0x1Full : 0ull) | (z2n ? 0x7E0ull : 0ull)
              | (z3n ? 0x7FF800ull : 0ull) | (z5n ? 0x1F800000ull : 0ull);

            // ===== adopt actual post(t+1); emit outputs =====
            float zt = sel_mask(zt0, zt1, mA);
            float vt = sel_mask(vt0, vt1, mA);
            float vx0 = sel_mask(vn00, vn10, mA);
            float vx1 = sel_mask(vn01, vn11, mA);
            v = sel_mask(vx0, vx1, mB);
            float ux0 = sel_mask(un00, un10, mA);
            float ux1 = sel_mask(un01, un11, mA);
            u = sel_mask(ux0, ux1, mB);
            float zx0 = sel_mask(zn00, zn10, mA);
            float zx1 = sel_mask(zn01, zn11, mA);
            float ztn = sel_mask(zx0, zx1, mB);

            zb[2 * j] = zt;  vb[2 * j] = vt;
            zb[2 * j + 1] = ztn;  vb[2 * j + 1] = v;

            z2c = z2n; z4c = z4n; z5c = z5n;
        }
        // batched flush (rows 16B-aligned at t; t % 8 == 0)
        *(float4*)(psp)     = make_float4(zb[0], zb[1], zb[2], zb[3]);
        *(float4*)(psp + 4) = make_float4(zb[4], zb[5], zb[6], zb[7]);
        *(float4*)(pvv)     = make_float4(vb[0], vb[1], vb[2], vb[3]);
        *(float4*)(pvv + 4) = make_float4(vb[4], vb[5], vb[6], vb[7]);
        psp += 8;
        pvv += 8;
    }
    // tail (T not divisible by 8), single-step variant; skipped if detected
    for (; t < T && t_det < 0; ++t) {
        float fI2 = z4c ? (z2c ? I2_11 : I2_01) : (z2c ? I2_10 : I2_00);
        float J0 = z5c ? C0b : C0a;
        float J1 = z5c ? C1b : C1a;
        J0 = is_g0 ? fI2 : J0;
        J1 = is_g0 ? fI2 : J1;
        float t1 = 0.04f * v;
        float t2 = t1 * v;
        float t3 = 5.0f * v;
        float t4 = t2 + t3;
        float t5 = t4 + 140.0f;
        float t6 = t5 - u;
        float bv = b * v;
        float bvu = bv - u;
        float du = ka * bvu;
        float u1 = u + du;
        float u1d = u1 + d;
        float t7_0 = t6 + J0;
        float dv_0 = 0.25f * t7_0;
        float v1t0 = v + dv_0;
        float t7_1 = t6 + J1;
        float dv_1 = 0.25f * t7_1;
        float v1t1 = v + dv_1;
        bool f0 = (v1t0 >= 30.0f);
        bool f1 = (v1t1 >= 30.0f);
        float vt0 = f0 ? c : v1t0;
        float ut0 = f0 ? u1d : u1;
        float vt1 = f1 ? c : v1t1;
        float ut1 = f1 ? u1d : u1;
        float zt0 = f0 ? 1.0f : 0.0f;
        float zt1 = f1 ? 1.0f : 0.0f;
        float btv = sel_tv1 ? v1t1 : v1t0;   // step-t slots only
        unsigned long long m = __ballot(btv >= 30.0f);
        int z2 = mbit(m, 0);
        int z3 = mbit(m, 5 + z2);
        int z4 = mbit(m, 11 + z3);
        int z5 = mbit(m, 17 + z3);
        unsigned long long mA =
            (z2 ? 0x7FFull : 0ull) | (z3 ? 0x7FF800ull : 0ull)
          | (z5 ? 0x1F800000ull : 0ull);
        v = sel_mask(vt0, vt1, mA);
        u = sel_mask(ut0, ut1, mA);
        psp[0] = sel_mask(zt0, zt1, mA);
        pvv[0] = v;
        ++psp; ++pvv;
        z2c = z2; z4c = z4; z5c = z5;
    }

    // publish detection result (ws is re-poisoned before every call)
    if (lane == 0) {
        ws[0] = (t_det >= 0) ? 1 : 0;
        ws[1] = t_det;
        ws[2] = Pf;
    }
}

// Fills out[r, t] for t in [t_det, T) with the periodic continuation
// out[r, t_det - P + ((t - t_det) mod P)]. No-op when no cycle was found.
__global__ __launch_bounds__(256) void fill_cycle(float* __restrict__ out,
                                                  const int* __restrict__ ws,
                                                  int T) {
    if (ws[0] == 0) return;
    const int t0 = ws[1];
    const int P  = ws[2];
    const int r  = blockIdx.y;                    // 0..9 (row)
    const float* __restrict__ src = out + (size_t)r * T + (t0 - P);
    float* __restrict__ dst       = out + (size_t)r * T + t0;
    const int n = T - t0;
    for (int i = blockIdx.x * blockDim.x + threadIdx.x; i < n;
         i += gridDim.x * blockDim.x) {
        dst[i] = src[i % P];
    }
}

extern "C" void kernel_launch(void* const* d_in, const int* in_sizes, int n_in,
                              void* d_out, int out_size, void* d_ws, size_t ws_size,
                              hipStream_t stream) {
    const float* mat = (const float*)d_in[0];
    const float* w   = (const float*)d_in[1];
    // out_size = 2 outputs * 5 neurons * T  -> T = out_size/10
    int T = out_size / 10;
    net_sim<<<1, 256, 0, stream>>>(mat, w, (float*)d_out, (int*)d_ws, T);
    dim3 grid(40, 10, 1);
    fill_cycle<<<grid, 256, 0, stream>>>((float*)d_out, (const int*)d_ws, T);
}

// Round 12
// 307.552 us; speedup vs baseline: 1.2320x; 1.2320x over previous
//
#include <hip/hip_runtime.h>

// Exact-order float32 arithmetic: numpy/jax evaluate left-to-right with no
// FMA contraction. hipcc defaults to -ffp-contract=fast, which would change
// rounding -> possible spike-time shift -> large voltage absmax error.
#pragma clang fp contract(off)

// R12 = EXACT R9 structure (verified pass: t_det=1720, P=40, absmax 0.0)
// with ONE change, isolated for bisection after R11's two-change failure:
//   * step body precomputes BOTH variant tails v1_0/v1_1 before the ballot
//     and adopts the actual one post-resolve with a single SGPR-mask
//     cndmask, removing the 4-hop actual-tail recompute from the carried
//     chain. sel(f(V0),f(V1)) == f(sel(V0,V1)) for the pure 3-op tail ->
//     bit-identical trajectory to R9.
// Detection (R9 verbatim): rolling anchor at t%40==0 (age-40 compare) +
// Brent pow-2 fallback compared at other 8-step block tops. State =
// {v,u} x 9 lanes + carry bits; bitwise equality => outputs repeat
// [anchor, t); fill_cycle copies the periodic continuation.
// Lane map (wave 0):
//   0   : LLBN (no speculation: I2 depends only on prev-step bits)
//   1,2 : EBN  variants z2 = 0,1
//   3,4 : IFN  variants z3 = 0,1
//   5,6 : TN   variants z3 = 0,1   (known z5p folded into candidates)
//   7,8 : MN   variants z5 = 0,1

__device__ __forceinline__ float sel_mask(float a, float b, unsigned long long m) {
    float r;
    // D = m.bit[lane] ? S1 : S0   (VOP3 v_cndmask with SGPR-pair condition)
    asm("v_cndmask_b32 %0, %1, %2, %3" : "=v"(r) : "v"(a), "v"(b), "s"(m));
    return r;
}

__global__ __launch_bounds__(256) void net_sim(const float* __restrict__ mat,
                                               const float* __restrict__ w,
                                               float* __restrict__ out,
                                               int* __restrict__ ws,
                                               int T) {
    __shared__ double red[256];
    const int tid = threadIdx.x;

    // ---- z_plus = sum(input_mat * w0), f32 products accumulated in f64 ----
    const float w0 = w[0];
    double s = 0.0;
    for (int i = tid; i < 127 * 127; i += 256) {
        float p = mat[i] * w0;   // elementwise product rounded to f32 (as ref)
        s += (double)p;
    }
    red[tid] = s;
    __syncthreads();
    #pragma unroll
    for (int off = 128; off > 0; off >>= 1) {
        if (tid < off) red[tid] += red[tid + off];
        __syncthreads();
    }
    if (tid >= 9) return;   // 9 lanes of wave 0 continue; no more barriers

    const float z_plus = (float)red[0];

    const float w2 = w[2], w3 = w[3], w5 = w[5], w6 = w[6], w7 = w[7],
                w8 = w[8], w9 = w[9], w10 = w[10], w11 = w[11];
    const float zp_w1 = z_plus * w[1];
    const float zp_w4 = z_plus * w[4];

    // Validated constant-I set (R2..R10, absmax 0.0). z*w is exactly +0.0f
    // or w; x + (+0.0f) == x for the values involved.
    const float I2_00 = w2 * (zp_w1 - 0.0f) + w3 * 0.0f;   // (z2p, z4p)
    const float I2_10 = w2 * (zp_w1 - 0.0f) + w3 * 1.0f;
    const float I2_01 = w2 * (zp_w1 - w7)   + w3 * 0.0f;
    const float I2_11 = w2 * (zp_w1 - w7)   + w3 * 1.0f;
    const float I3_0  = zp_w4 + 0.0f * w5;
    const float I3_1  = zp_w4 + 1.0f * w5;
    const float I4_0  = 0.0f * w6;
    const float I4_1  = 1.0f * w6;
    const float I5_00 = w9 * (0.0f * w8) + w10 * 0.0f;     // (z3, z5p)
    const float I5_10 = w9 * (1.0f * w8) + w10 * 0.0f;
    const float I5_01 = w9 * (0.0f * w8) + w10 * 1.0f;
    const float I5_11 = w9 * (1.0f * w8) + w10 * 1.0f;
    const float I6_0  = 0.0f * w11;
    const float I6_1  = 1.0f * w11;

    const int lane = tid;  // 0..8
    const int g = lane == 0 ? 0 : lane <= 2 ? 1 : lane <= 4 ? 2 : lane <= 6 ? 3 : 4;

    // per-lane params; ka = float(TAU*DT*a) computed in f64 like Python
    const float ka = lane == 0 ? (float)(0.25 * 0.1) : (float)(0.25 * 0.02);
    const float b  = lane == 0 ? -0.075f : (g == 3 ? 0.2f : 0.25f);
    const float c  = g <= 1 ? -55.0f : -65.0f;
    const float d  = g == 1 ? 0.05f : 6.0f;
    float v = g == 0 ? -60.0f : (g == 3 ? -70.0f : -64.0f);
    float u = g == 0 ? 4.5f   : (g == 3 ? -14.0f : -16.0f);

    // candidate-I vectors: variant0/variant1 per group, for z5p=0(a)/1(b).
    const float C0a = g == 0 ? I2_00 : g == 1 ? I3_0 : g == 2 ? I4_0
                    : g == 3 ? I5_00 : I6_0;
    const float C0b = g == 0 ? I2_00 : g == 1 ? I3_0 : g == 2 ? I4_0
                    : g == 3 ? I5_01 : I6_0;
    const float C1a = g == 1 ? I3_1 : g == 2 ? I4_1 : g == 3 ? I5_10
                    : g == 4 ? I6_1 : 0.0f;
    const float C1b = g == 1 ? I3_1 : g == 2 ? I4_1 : g == 3 ? I5_11
                    : g == 4 ? I6_1 : 0.0f;

    const bool is_lane0  = (lane == 0);
    const bool spec_var1 = (lane == 2) | (lane == 4) | (lane == 6) | (lane == 8);

    float* __restrict__ psp = out + g * T;           // spikes row
    float* __restrict__ pvv = out + 5 * T + g * T;   // volts row

    int z2 = 0, z4 = 0, z5 = 0;   // prev-step bits (z2p, z4p, z5p) — uniform

    // ---- cycle-detection: rolling-40 anchor + Brent pow-2 fallback (R9) --
    float rav = 0.0f, rau = 0.0f; int raz2 = 0, raz4 = 0, raz5 = 0, ra_t = -1;
    float cav = 0.0f, cau = 0.0f; int caz2 = 0, caz4 = 0, caz5 = 0, ca_t = -1;
    int next_coarse = 8;
    int t_det = -1, Pf = 0;

    float zb[8], vb[8];

    int t = 0;
    for (; t + 8 <= T; t += 8) {
        // ---- block top: anchor compares / refresh (R9 verbatim) ----
        if (t % 40 == 0) {
            if (ra_t >= 0) {
                unsigned long long mv =
                    __ballot(__float_as_uint(v) == __float_as_uint(rav));
                unsigned long long mu =
                    __ballot(__float_as_uint(u) == __float_as_uint(rau));
                if (((mv & mu) & 0x1FFull) == 0x1FFull &&
                    z2 == raz2 && z4 == raz4 && z5 == raz5) {
                    t_det = t; Pf = t - ra_t;   // Pf == 40
                    break;
                }
            }
            if (t) { rav = v; rau = u; raz2 = z2; raz4 = z4; raz5 = z5; ra_t = t; }
        } else if (ca_t >= 0) {
            unsigned long long mv =
                __ballot(__float_as_uint(v) == __float_as_uint(cav));
            unsigned long long mu =
                __ballot(__float_as_uint(u) == __float_as_uint(cau));
            if (((mv & mu) & 0x1FFull) == 0x1FFull &&
                z2 == caz2 && z4 == caz4 && z5 == caz5) {
                t_det = t; Pf = t - ca_t;
                break;
            }
        }
        if (t == next_coarse) {
            cav = v; cau = u; caz2 = z2; caz4 = z4; caz5 = z5; ca_t = t;
            next_coarse <<= 1;
        }

        #pragma unroll
        for (int j = 0; j < 8; ++j) {
            // candidate-I prep from prev-step bits (off critical path)
            float fI2 = z4 ? (z2 ? I2_11 : I2_01) : (z2 ? I2_10 : I2_00);
            float V0 = z5 ? C0b : C0a;
            float V1 = z5 ? C1b : C1a;
            V0 = is_lane0 ? fI2 : V0;
            V1 = is_lane0 ? fI2 : V1;

            // common izh head (I-independent)
            float t1 = 0.04f * v;
            float t2 = t1 * v;
            float t3 = 5.0f * v;
            float t4 = t2 + t3;
            float t5 = t4 + 140.0f;
            float t6 = t5 - u;
            float bv = b * v;
            float bvu = bv - u;
            float du = ka * bvu;
            float u1 = u + du;
            float u1d = u1 + d;

            // both variant tails (parallel, pre-ballot) — R12's one change
            float t7_0 = t6 + V0;
            float dv_0 = 0.25f * t7_0;   // TAU*DT = 0.25 exactly
            float v1_0 = v + dv_0;
            float t7_1 = t6 + V1;
            float dv_1 = 0.25f * t7_1;
            float v1_1 = v + dv_1;

            // single ballot on each lane's assigned variant (same as R9)
            float v1b = spec_var1 ? v1_1 : v1_0;
            unsigned long long m = __ballot(v1b >= 30.0f);

            // scalar resolution (uniform, R9 verbatim)
            int nz2 = (int)(m & 1ull);
            int z3  = (int)((m >> (1 + nz2)) & 1ull);
            int nz4 = (int)((m >> (3 + z3)) & 1ull);
            int nz5 = (int)((m >> (5 + z3)) & 1ull);
            unsigned long long ssel =
                (nz2 ? 0x006ull : 0ull) | (z3 ? 0x078ull : 0ull)
              | (nz5 ? 0x180ull : 0ull);

            // adopt the actual variant (one cndmask), fire/reset locally
            float v1a = sel_mask(v1_0, v1_1, ssel);
            bool fa = (v1a >= 30.0f);
            v = fa ? c : v1a;
            u = fa ? u1d : u1;           // z*d is exactly d or +0.0f

            zb[j] = fa ? 1.0f : 0.0f;
            vb[j] = v;

            z2 = nz2; z4 = nz4; z5 = nz5;
        }
        // batched flush (rows 16B-aligned at t; t % 8 == 0)
        *(float4*)(psp)     = make_float4(zb[0], zb[1], zb[2], zb[3]);
        *(float4*)(psp + 4) = make_float4(zb[4], zb[5], zb[6], zb[7]);
        *(float4*)(pvv)     = make_float4(vb[0], vb[1], vb[2], vb[3]);
        *(float4*)(pvv + 4) = make_float4(vb[4], vb[5], vb[6], vb[7]);
        psp += 8;
        pvv += 8;
    }
    // tail (T not divisible by 8), only when no cycle was detected
    for (; t < T && t_det < 0; ++t) {
        float fI2 = z4 ? (z2 ? I2_11 : I2_01) : (z2 ? I2_10 : I2_00);
        float V0 = z5 ? C0b : C0a;
        float V1 = z5 ? C1b : C1a;
        V0 = is_lane0 ? fI2 : V0;
        V1 = is_lane0 ? fI2 : V1;
        float t1 = 0.04f * v;
        float t2 = t1 * v;
        float t3 = 5.0f * v;
        float t4 = t2 + t3;
        float t5 = t4 + 140.0f;
        float t6 = t5 - u;
        float bv = b * v;
        float bvu = bv - u;
        float du = ka * bvu;
        float u1 = u + du;
        float u1d = u1 + d;
        float t7_0 = t6 + V0;
        float dv_0 = 0.25f * t7_0;
        float v1_0 = v + dv_0;
        float t7_1 = t6 + V1;
        float dv_1 = 0.25f * t7_1;
        float v1_1 = v + dv_1;
        float v1b = spec_var1 ? v1_1 : v1_0;
        unsigned long long m = __ballot(v1b >= 30.0f);
        int nz2 = (int)(m & 1ull);
        int z3  = (int)((m >> (1 + nz2)) & 1ull);
        int nz4 = (int)((m >> (3 + z3)) & 1ull);
        int nz5 = (int)((m >> (5 + z3)) & 1ull);
        unsigned long long ssel =
            (nz2 ? 0x006ull : 0ull) | (z3 ? 0x078ull : 0ull)
          | (nz5 ? 0x180ull : 0ull);
        float v1a = sel_mask(v1_0, v1_1, ssel);
        bool fa = (v1a >= 30.0f);
        v = fa ? c : v1a;
        u = fa ? u1d : u1;
        psp[0] = fa ? 1.0f : 0.0f;
        pvv[0] = v;
        ++psp; ++pvv;
        z2 = nz2; z4 = nz4; z5 = nz5;
    }

    // publish detection result (ws is re-poisoned before every call)
    if (lane == 0) {
        ws[0] = (t_det >= 0) ? 1 : 0;
        ws[1] = t_det;
        ws[2] = Pf;
    }
}

// Fills out[r, t] for t in [t_det, T) with the periodic continuation
// out[r, t_det - P + ((t - t_det) mod P)]. No-op when no cycle was found.
__global__ __launch_bounds__(256) void fill_cycle(float* __restrict__ out,
                                                  const int* __restrict__ ws,
                                                  int T) {
    if (ws[0] == 0) return;
    const int t0 = ws[1];
    const int P  = ws[2];
    const int r  = blockIdx.y;                    // 0..9 (row)
    const float* __restrict__ src = out + (size_t)r * T + (t0 - P);
    float* __restrict__ dst       = out + (size_t)r * T + t0;
    const int n = T - t0;
    for (int i = blockIdx.x * blockDim.x + threadIdx.x; i < n;
         i += gridDim.x * blockDim.x) {
        dst[i] = src[i % P];
    }
}

extern "C" void kernel_launch(void* const* d_in, const int* in_sizes, int n_in,
                              void* d_out, int out_size, void* d_ws, size_t ws_size,
                              hipStream_t stream) {
    const float* mat = (const float*)d_in[0];
    const float* w   = (const float*)d_in[1];
    // out_size = 2 outputs * 5 neurons * T  -> T = out_size/10
    int T = out_size / 10;
    net_sim<<<1, 256, 0, stream>>>(mat, w, (float*)d_out, (int*)d_ws, T);
    dim3 grid(40, 10, 1);
    fill_cycle<<<grid, 256, 0, stream>>>((float*)d_out, (const int*)d_ws, T);
}

// Round 13
// 300.215 us; speedup vs baseline: 1.2621x; 1.0244x over previous
//
#include <hip/hip_runtime.h>

// Exact-order float32 arithmetic: numpy/jax evaluate left-to-right with no
// FMA contraction. hipcc defaults to -ffp-contract=fast, which would change
// rounding -> possible spike-time shift -> large voltage absmax error.
#pragma clang fp contract(off)

// R13 = EXACT R9 (best measured: net_sim 267 us, t_det=1720, P=40,
// absmax 0.0) with one off-chain micro-cut: the block-top t%40 test is a
// mod-5 block counter (R9 used an integer modulo -> magic-mul chain).
// Step body, detection semantics, flush, fill_cycle: R9 verbatim.
// Lane map (wave 0):
//   0   : LLBN (no speculation: I2 depends only on prev-step bits)
//   1,2 : EBN  speculating z2 = 0,1
//   3,4 : IFN  speculating z3 = 0,1
//   5,6 : TN   speculating z3 = 0,1   (known z5p folded into candidates)
//   7,8 : MN   speculating z5 = 0,1
// Per step: candidate-I prep -> common izh head -> speculative ballot tail
// -> scalar resolve (z2,z3,z4,z5) -> actual tail recomputed locally with
// the I selected by an SGPR-pair-mask cndmask -> fire/reset -> buffered
// stores (float4 flush per 8 steps).
// Cycle detection: state = {v,u} x 9 lanes + carry bits. Bitwise equality
// with a 40-step-old rolling anchor (checked when the block counter wraps,
// i.e. t % 40 == 0) => outputs repeat [t-40, t); Brent pow-2 anchors as
// generic fallback at the other block tops. fill_cycle copies the
// periodic continuation.

__device__ __forceinline__ float sel_mask(float a, float b, unsigned long long m) {
    float r;
    // D = m.bit[lane] ? S1 : S0   (VOP3 v_cndmask with SGPR-pair condition)
    asm("v_cndmask_b32 %0, %1, %2, %3" : "=v"(r) : "v"(a), "v"(b), "s"(m));
    return r;
}

__global__ __launch_bounds__(256) void net_sim(const float* __restrict__ mat,
                                               const float* __restrict__ w,
                                               float* __restrict__ out,
                                               int* __restrict__ ws,
                                               int T) {
    __shared__ double red[256];
    const int tid = threadIdx.x;

    // ---- z_plus = sum(input_mat * w0), f32 products accumulated in f64 ----
    const float w0 = w[0];
    double s = 0.0;
    for (int i = tid; i < 127 * 127; i += 256) {
        float p = mat[i] * w0;   // elementwise product rounded to f32 (as ref)
        s += (double)p;
    }
    red[tid] = s;
    __syncthreads();
    #pragma unroll
    for (int off = 128; off > 0; off >>= 1) {
        if (tid < off) red[tid] += red[tid + off];
        __syncthreads();
    }
    if (tid >= 9) return;   // 9 lanes of wave 0 continue; no more barriers

    const float z_plus = (float)red[0];

    const float w2 = w[2], w3 = w[3], w5 = w[5], w6 = w[6], w7 = w[7],
                w8 = w[8], w9 = w[9], w10 = w[10], w11 = w[11];
    const float zp_w1 = z_plus * w[1];
    const float zp_w4 = z_plus * w[4];

    // Validated constant-I set (R2..R12, absmax 0.0). z*w is exactly +0.0f
    // or w; x + (+0.0f) == x for the values involved.
    const float I2_00 = w2 * (zp_w1 - 0.0f) + w3 * 0.0f;   // (z2p, z4p)
    const float I2_10 = w2 * (zp_w1 - 0.0f) + w3 * 1.0f;
    const float I2_01 = w2 * (zp_w1 - w7)   + w3 * 0.0f;
    const float I2_11 = w2 * (zp_w1 - w7)   + w3 * 1.0f;
    const float I3_0  = zp_w4 + 0.0f * w5;
    const float I3_1  = zp_w4 + 1.0f * w5;
    const float I4_0  = 0.0f * w6;
    const float I4_1  = 1.0f * w6;
    const float I5_00 = w9 * (0.0f * w8) + w10 * 0.0f;     // (z3, z5p)
    const float I5_10 = w9 * (1.0f * w8) + w10 * 0.0f;
    const float I5_01 = w9 * (0.0f * w8) + w10 * 1.0f;
    const float I5_11 = w9 * (1.0f * w8) + w10 * 1.0f;
    const float I6_0  = 0.0f * w11;
    const float I6_1  = 1.0f * w11;

    const int lane = tid;  // 0..8
    const int g = lane == 0 ? 0 : lane <= 2 ? 1 : lane <= 4 ? 2 : lane <= 6 ? 3 : 4;

    // per-lane params; ka = float(TAU*DT*a) computed in f64 like Python
    const float ka = lane == 0 ? (float)(0.25 * 0.1) : (float)(0.25 * 0.02);
    const float b  = lane == 0 ? -0.075f : (g == 3 ? 0.2f : 0.25f);
    const float c  = g <= 1 ? -55.0f : -65.0f;
    const float d  = g == 1 ? 0.05f : 6.0f;
    float v = g == 0 ? -60.0f : (g == 3 ? -70.0f : -64.0f);
    float u = g == 0 ? 4.5f   : (g == 3 ? -14.0f : -16.0f);

    // candidate-I vectors: variant0/variant1 per group, for z5p=0(a)/1(b).
    const float C0a = g == 0 ? I2_00 : g == 1 ? I3_0 : g == 2 ? I4_0
                    : g == 3 ? I5_00 : I6_0;
    const float C0b = g == 0 ? I2_00 : g == 1 ? I3_0 : g == 2 ? I4_0
                    : g == 3 ? I5_01 : I6_0;
    const float C1a = g == 1 ? I3_1 : g == 2 ? I4_1 : g == 3 ? I5_10
                    : g == 4 ? I6_1 : 0.0f;
    const float C1b = g == 1 ? I3_1 : g == 2 ? I4_1 : g == 3 ? I5_11
                    : g == 4 ? I6_1 : 0.0f;

    const bool is_lane0  = (lane == 0);
    const bool spec_var1 = (lane == 2) | (lane == 4) | (lane == 6) | (lane == 8);

    float* __restrict__ psp = out + g * T;           // spikes row
    float* __restrict__ pvv = out + 5 * T + g * T;   // volts row

    int z2 = 0, z4 = 0, z5 = 0;   // prev-step bits (z2p, z4p, z5p) — uniform

    // ---- cycle-detection: rolling-40 anchor + Brent pow-2 fallback ----
    float rav = 0.0f, rau = 0.0f; int raz2 = 0, raz4 = 0, raz5 = 0, ra_t = -1;
    float cav = 0.0f, cau = 0.0f; int caz2 = 0, caz4 = 0, caz5 = 0, ca_t = -1;
    int next_coarse = 8;
    int t_det = -1, Pf = 0;
    int blk5 = 0;   // t/8 mod 5; 0 <=> t % 40 == 0

    float zb[8], vb[8];

    int t = 0;
    for (; t + 8 <= T; t += 8) {
        // ---- block top: anchor compares / refresh (R9 semantics) ----
        if (blk5 == 0) {
            if (ra_t >= 0) {
                unsigned long long mv =
                    __ballot(__float_as_uint(v) == __float_as_uint(rav));
                unsigned long long mu =
                    __ballot(__float_as_uint(u) == __float_as_uint(rau));
                if (((mv & mu) & 0x1FFull) == 0x1FFull &&
                    z2 == raz2 && z4 == raz4 && z5 == raz5) {
                    t_det = t; Pf = t - ra_t;   // Pf == 40
                    break;
                }
            }
            if (t) { rav = v; rau = u; raz2 = z2; raz4 = z4; raz5 = z5; ra_t = t; }
        } else if (ca_t >= 0) {
            unsigned long long mv =
                __ballot(__float_as_uint(v) == __float_as_uint(cav));
            unsigned long long mu =
                __ballot(__float_as_uint(u) == __float_as_uint(cau));
            if (((mv & mu) & 0x1FFull) == 0x1FFull &&
                z2 == caz2 && z4 == caz4 && z5 == caz5) {
                t_det = t; Pf = t - ca_t;
                break;
            }
        }
        if (t == next_coarse) {
            cav = v; cau = u; caz2 = z2; caz4 = z4; caz5 = z5; ca_t = t;
            next_coarse <<= 1;
        }
        blk5 = (blk5 == 4) ? 0 : (blk5 + 1);

        #pragma unroll
        for (int j = 0; j < 8; ++j) {
            // candidate-I prep from prev-step bits (off critical path)
            float fI2 = z4 ? (z2 ? I2_11 : I2_01) : (z2 ? I2_10 : I2_00);
            float V0 = z5 ? C0b : C0a;
            float V1 = z5 ? C1b : C1a;
            V0 = is_lane0 ? fI2 : V0;
            float Ib = spec_var1 ? V1 : V0;

            // common izh head (I-independent)
            float t1 = 0.04f * v;
            float t2 = t1 * v;
            float t3 = 5.0f * v;
            float t4 = t2 + t3;
            float t5 = t4 + 140.0f;
            float t6 = t5 - u;
            float bv = b * v;
            float bvu = bv - u;
            float du = ka * bvu;
            float u1 = u + du;

            // speculative (ballot) tail
            float t7b = t6 + Ib;
            float dvb = 0.25f * t7b;     // TAU*DT = 0.25 exactly
            float v1b = v + dvb;
            unsigned long long m = __ballot(v1b >= 30.0f);

            // scalar resolution (uniform)
            int nz2 = (int)(m & 1ull);
            int z3  = (int)((m >> (1 + nz2)) & 1ull);
            int nz4 = (int)((m >> (3 + z3)) & 1ull);
            int nz5 = (int)((m >> (5 + z3)) & 1ull);
            unsigned long long ssel =
                (nz2 ? 0x006ull : 0ull) | (z3 ? 0x078ull : 0ull)
              | (nz5 ? 0x180ull : 0ull);

            // actual tail, recomputed locally; I select via SGPR-pair mask
            float Ia = sel_mask(V0, V1, ssel);
            float t7a = t6 + Ia;
            float dva = 0.25f * t7a;
            float v1a = v + dva;
            bool fa = (v1a >= 30.0f);
            v = fa ? c : v1a;
            float u1d = u1 + d;
            u = fa ? u1d : u1;           // z*d is exactly d or +0.0f

            zb[j] = fa ? 1.0f : 0.0f;
            vb[j] = v;

            z2 = nz2; z4 = nz4; z5 = nz5;
        }
        // batched flush (rows 16B-aligned at t; t % 8 == 0)
        *(float4*)(psp)     = make_float4(zb[0], zb[1], zb[2], zb[3]);
        *(float4*)(psp + 4) = make_float4(zb[4], zb[5], zb[6], zb[7]);
        *(float4*)(pvv)     = make_float4(vb[0], vb[1], vb[2], vb[3]);
        *(float4*)(pvv + 4) = make_float4(vb[4], vb[5], vb[6], vb[7]);
        psp += 8;
        pvv += 8;
    }
    // tail (T not divisible by 8), only when no cycle was detected
    for (; t < T && t_det < 0; ++t) {
        float fI2 = z4 ? (z2 ? I2_11 : I2_01) : (z2 ? I2_10 : I2_00);
        float V0 = z5 ? C0b : C0a;
        float V1 = z5 ? C1b : C1a;
        V0 = is_lane0 ? fI2 : V0;
        float Ib = spec_var1 ? V1 : V0;
        float t1 = 0.04f * v;
        float t2 = t1 * v;
        float t3 = 5.0f * v;
        float t4 = t2 + t3;
        float t5 = t4 + 140.0f;
        float t6 = t5 - u;
        float bv = b * v;
        float bvu = bv - u;
        float du = ka * bvu;
        float u1 = u + du;
        float t7b = t6 + Ib;
        float dvb = 0.25f * t7b;
        float v1b = v + dvb;
        unsigned long long m = __ballot(v1b >= 30.0f);
        int nz2 = (int)(m & 1ull);
        int z3  = (int)((m >> (1 + nz2)) & 1ull);
        int nz4 = (int)((m >> (3 + z3)) & 1ull);
        int nz5 = (int)((m >> (5 + z3)) & 1ull);
        unsigned long long ssel =
            (nz2 ? 0x006ull : 0ull) | (z3 ? 0x078ull : 0ull)
          | (nz5 ? 0x180ull : 0ull);
        float Ia = sel_mask(V0, V1, ssel);
        float t7a = t6 + Ia;
        float dva = 0.25f * t7a;
        float v1a = v + dva;
        bool fa = (v1a >= 30.0f);
        v = fa ? c : v1a;
        float u1d = u1 + d;
        u = fa ? u1d : u1;
        psp[0] = fa ? 1.0f : 0.0f;
        pvv[0] = v;
        ++psp; ++pvv;
        z2 = nz2; z4 = nz4; z5 = nz5;
    }

    // publish detection result (ws is re-poisoned before every call)
    if (lane == 0) {
        ws[0] = (t_det >= 0) ? 1 : 0;
        ws[1] = t_det;
        ws[2] = Pf;
    }
}

// Fills out[r, t] for t in [t_det, T) with the periodic continuation
// out[r, t_det - P + ((t - t_det) mod P)]. No-op when no cycle was found.
__global__ __launch_bounds__(256) void fill_cycle(float* __restrict__ out,
                                                  const int* __restrict__ ws,
                                                  int T) {
    if (ws[0] == 0) return;
    const int t0 = ws[1];
    const int P  = ws[2];
    const int r  = blockIdx.y;                    // 0..9 (row)
    const float* __restrict__ src = out + (size_t)r * T + (t0 - P);
    float* __restrict__ dst       = out + (size_t)r * T + t0;
    const int n = T - t0;
    for (int i = blockIdx.x * blockDim.x + threadIdx.x; i < n;
         i += gridDim.x * blockDim.x) {
        dst[i] = src[i % P];
    }
}

extern "C" void kernel_launch(void* const* d_in, const int* in_sizes, int n_in,
                              void* d_out, int out_size, void* d_ws, size_t ws_size,
                              hipStream_t stream) {
    const float* mat = (const float*)d_in[0];
    const float* w   = (const float*)d_in[1];
    // out_size = 2 outputs * 5 neurons * T  -> T = out_size/10
    int T = out_size / 10;
    net_sim<<<1, 256, 0, stream>>>(mat, w, (float*)d_out, (int*)d_ws, T);
    dim3 grid(40, 10, 1);
    fill_cycle<<<grid, 256, 0, stream>>>((float*)d_out, (const int*)d_ws, T);
}